// Round 1
// baseline (226.556 us; speedup 1.0000x reference)
//
#include <hip/hip_runtime.h>
#include <hip/hip_bf16.h>

// Problem constants: B=64, S=512, H=768, L=9
#define NB 64
#define NS 512
#define NH 768
#define NL 9
#define NROWS (NB*NS)          // 32768
#define EMN (NROWS*NL)         // 294912

__device__ __forceinline__ float readlane_f(float v, int l) {
    return __int_as_float(__builtin_amdgcn_readlane(__float_as_int(v), l));
}
__device__ __forceinline__ unsigned long long readlane_u64(unsigned long long v, int l) {
    unsigned int lo = (unsigned int)__builtin_amdgcn_readlane((int)(unsigned int)(v & 0xffffffffULL), l);
    unsigned int hi = (unsigned int)__builtin_amdgcn_readlane((int)(unsigned int)(v >> 32), l);
    return ((unsigned long long)hi << 32) | (unsigned long long)lo;
}
// DPP add: x += dpp_move(x, CTRL); out-of-bound source lanes contribute 0.
template <int CTRL>
__device__ __forceinline__ float dpp_add(float x) {
    int t = __builtin_amdgcn_update_dpp(0, __float_as_int(x), CTRL, 0xf, 0xf, false);
    return x + __int_as_float(t);
}

// ---------------- Kernel A: emissions GEMM (K split across waves) ----------------
// 8192 blocks x 256 thr; block handles rows 4bx..4bx+3.
// Wave w owns k-range [192w, 192w+192); lane l owns k in {192w+l+64c, c=0..2}.
// Reduction: ONE dpp level (pair sums at odd lanes) + LDS combine that replicates
// the exact pairwise tree the old 6-level DPP reduce produced (bitwise identical,
// fp add is commutative), saving ~360 VALU instrs/thread vs the 6-level version.
__global__ __launch_bounds__(256) void k_gemm(const float* __restrict__ hidden,
                                              const float* __restrict__ W,
                                              const float* __restrict__ bias,
                                              float* __restrict__ em,
                                              float* __restrict__ out) {
    __shared__ float s_part[4][4][32][NL];   // [wave][row][pair-group][j] = 18.4KB
    int tid = threadIdx.x;
    int lane = tid & 63;
    int w = tid >> 6;
    int bx = blockIdx.x;
    if (bx == 0 && tid == 0) { out[0] = 0.f; out[1] = 0.f; }

    int kbase = 192 * w + lane;          // + 64c, c=0..2
    // preload W: 27 scalars, lane-stride 36B (L2-hot after first blocks)
    float Wv[3][NL];
#pragma unroll
    for (int c = 0; c < 3; c++) {
        const float* wp = W + (size_t)(kbase + 64 * c) * NL;
#pragma unroll
        for (int j = 0; j < NL; j++) Wv[c][j] = wp[j];
    }

    int g = lane >> 1;
    bool odd = (lane & 1) != 0;

#pragma unroll
    for (int r = 0; r < 4; r++) {
        int row = 4 * bx + r;
        const float* hp = hidden + (size_t)row * NH + kbase;
        float h0 = hp[0], h1 = hp[64], h2 = hp[128];
        float acc[NL];
#pragma unroll
        for (int j = 0; j < NL; j++) {
            acc[j] = fmaf(h0, Wv[0][j], fmaf(h1, Wv[1][j], h2 * Wv[2][j]));
        }
        // one DPP level: odd lane holds x_{l} + x_{l-1}  (exact old tree leaves)
#pragma unroll
        for (int j = 0; j < NL; j++) acc[j] = dpp_add<0x111>(acc[j]);
        if (odd) {
#pragma unroll
            for (int j = 0; j < NL; j++) s_part[w][r][g][j] = acc[j];
        }
    }
    __syncthreads();
    if (tid < 36) {
        int r = tid / NL, j = tid % NL;
        float sw[4];
#pragma unroll
        for (int ww = 0; ww < 4; ww++) {
            const float* p = &s_part[ww][r][0][j];
            // rebuild the exact old pairwise tree:
            // G_k = (P_{4k+3}+P_{4k+2}) + (P_{4k+1}+P_{4k})
            float G[8];
#pragma unroll
            for (int k = 0; k < 8; k++) {
                G[k] = (p[(4 * k + 3) * NL] + p[(4 * k + 2) * NL]) +
                       (p[(4 * k + 1) * NL] + p[(4 * k + 0) * NL]);
            }
            sw[ww] = ((G[6] + G[7]) + (G[4] + G[5])) + ((G[2] + G[3]) + (G[0] + G[1]));
        }
        float v = (sw[0] + sw[1]) + (sw[2] + sw[3]) + bias[j];
        em[(size_t)(4 * bx + r) * NL + j] = v;
    }
}

// ---------------- Kernel B: DP + finalize ----------------
// blocks [0,64):   wave0 = forward algorithm -> atomicAdd(loss, +logZ/64)
//                  wave1 = gold-path numerator -> atomicAdd(loss, -score/64)
// blocks [64,128): Viterbi fwd + backpointers + backtrack + predict/label/correct
__global__ __launch_bounds__(256) void k_dp(const float* __restrict__ em,
                                            const int* __restrict__ label,
                                            const int* __restrict__ mask,
                                            const float* __restrict__ startT,
                                            const float* __restrict__ endT,
                                            const float* __restrict__ trans,
                                            float* __restrict__ out) {
    __shared__ float s_em[(NS + 1) * NL];    // +NL pad so 2-ahead prefetch never OOB
    __shared__ float s_v[NS * NL];           // 18KB viterbi value history
    __shared__ unsigned char s_bp[NS * NL];  // 4.6KB backpointers
    __shared__ unsigned char s_path[NS];     // decoded path
    __shared__ int s_mk[NS + 4];             // mask (+pad for prefetch)
    __shared__ float s_T[NL * NL];

    int bx = blockIdx.x;
    int tid = threadIdx.x;
    int lane = tid & 63;
    int b = bx & 63;

    // ---- common staging (coalesced) ----
    {
        const float4* ef = (const float4*)(em + (size_t)b * NS * NL);
        float4* sf = (float4*)s_em;
        for (int q = tid; q < NS * NL / 4; q += 256) sf[q] = ef[q];
        if (tid < NS / 4) ((int4*)s_mk)[tid] = ((const int4*)(mask + b * NS))[tid];
        if (tid < NL * NL) s_T[tid] = trans[tid];
    }
    __syncthreads();

    if (bx < NB) {
        if (tid < 64) {
            // ---- forward algorithm (linear domain, exact pow2 renorm) ----
            int j9 = tid < NL ? tid : NL - 1;
            float Mcol[NL];
#pragma unroll
            for (int i = 0; i < NL; i++) Mcol[i] = __expf(s_T[i * NL + j9]);
            float a = __expf(startT[j9] + s_em[j9]);
            int eacc = 0;
            const float* emp = s_em + j9;
            float xA = __expf(emp[1 * NL]), xB = __expf(emp[2 * NL]);
            int mA = s_mk[1], mB = s_mk[2];

#define FSTEP_CORE(XE_, MV_) do { \
    float p0 = readlane_f(a, 0) * Mcol[0]; \
    float p1 = readlane_f(a, 1) * Mcol[1]; \
    float p2 = readlane_f(a, 2) * Mcol[2]; \
    float p3 = readlane_f(a, 3) * Mcol[3]; \
    float p4 = readlane_f(a, 4) * Mcol[4]; \
    float p5 = readlane_f(a, 5) * Mcol[5]; \
    float p6 = readlane_f(a, 6) * Mcol[6]; \
    float p7 = readlane_f(a, 7) * Mcol[7]; \
    float p8 = readlane_f(a, 8) * Mcol[8]; \
    float s_ = (((p0 + p1) + (p2 + p3)) + ((p4 + p5) + (p6 + p7))) + p8; \
    float an_ = (XE_) * s_; \
    a = ((MV_) > 0) ? an_ : a; \
} while (0)

#define FRENORM(T_) do { \
    if (((T_) & 7) == 0) { \
        float c0 = readlane_f(a, 0), c1 = readlane_f(a, 1), c2 = readlane_f(a, 2); \
        float c3 = readlane_f(a, 3), c4 = readlane_f(a, 4), c5 = readlane_f(a, 5); \
        float c6 = readlane_f(a, 6), c7 = readlane_f(a, 7), c8 = readlane_f(a, 8); \
        float c_ = (((c0 + c1) + (c2 + c3)) + ((c4 + c5) + (c6 + c7))) + c8; \
        int ex_ = ((__float_as_int(c_) >> 23) & 255) - 127; \
        a = ldexpf(a, -ex_); \
        eacc += ex_; \
    } \
} while (0)

            for (int t = 1; t < NS - 2; t += 2) {
                float xC = __expf(emp[(t + 2) * NL]);
                float xD = __expf(emp[(t + 3) * NL]);
                int mC = s_mk[t + 2], mD = s_mk[t + 3];
                FSTEP_CORE(xA, mA);        // t odd: (t&7)==0 impossible
                FSTEP_CORE(xB, mB);
                FRENORM(t + 1);            // even slot: t+1 = 8,16,...,504 (same cadence)
                xA = xC; xB = xD; mA = mC; mB = mD;
            }
            FSTEP_CORE(xA, mA);            // t = 511 (511&7==7, no renorm)
#undef FSTEP_CORE
#undef FRENORM
            float z = a * __expf(endT[j9]);
            float c0 = readlane_f(z, 0), c1 = readlane_f(z, 1), c2 = readlane_f(z, 2);
            float c3 = readlane_f(z, 3), c4 = readlane_f(z, 4), c5 = readlane_f(z, 5);
            float c6 = readlane_f(z, 6), c7 = readlane_f(z, 7), c8 = readlane_f(z, 8);
            float c = (((c0 + c1) + (c2 + c3)) + ((c4 + c5) + (c6 + c7))) + c8;
            if (tid == 0) {
                float lz = (float)eacc * 0.6931471805599453f + __logf(c);
                atomicAdd(out, lz * (1.0f / (float)NB));
            }
        } else if (tid < 128) {
            // ---- numerator (gold path score) ----
            const int* lb = label + b * NS;
            int t0 = lane * 8;
            int lab[8]; int mk[8];
#pragma unroll
            for (int r = 0; r < 8; r++) { lab[r] = lb[t0 + r]; mk[r] = s_mk[t0 + r]; }
            if (lane == 0) mk[0] = 1;
            int h = 0, sl = 0;
#pragma unroll
            for (int r = 0; r < 8; r++) { if (mk[r] > 0) { h = 1; sl = lab[r]; } }
#pragma unroll
            for (int d = 1; d < 64; d <<= 1) {
                int ho = __shfl_up(h, d);
                int so = __shfl_up(sl, d);
                if (!h) { h = ho; sl = so; }
            }
            int lg = __shfl(sl, 63);
            int incoming = __shfl_up(sl, 1);
            float sc = 0.f;
            int prevr = (lane == 0) ? lab[0] : incoming;
#pragma unroll
            for (int r = 0; r < 8; r++) {
                int t = t0 + r;
                if (t > 0) {
                    float s = s_T[prevr * NL + lab[r]] + s_em[t * NL + lab[r]];
                    sc += s * (float)mk[r];
                }
                if (mk[r] > 0) prevr = lab[r];
            }
            if (lane == 0) {
                int g0 = lab[0];
                sc += startT[g0] + s_em[g0] + endT[lg];
            }
#pragma unroll
            for (int d = 1; d < 64; d <<= 1) sc += __shfl_xor(sc, d);
            if (lane == 0) atomicAdd(out, -sc * (1.0f / (float)NB));
        }
    } else {
        // ---- Viterbi phase 1: serial value chain (bit-exact; max is order-free,
        //      and fl(max_i(v_i+T_i)+e) == max_i fl((v_i+T_i)+e) by monotonicity) ----
        if (tid < 64) {
            int j9 = tid < NL ? tid : NL - 1;
            float Tcol[NL];
#pragma unroll
            for (int i = 0; i < NL; i++) Tcol[i] = s_T[i * NL + j9];
            float v = startT[j9] + s_em[j9];
            if (tid < NL) s_v[tid] = v;
            const float* emp = s_em + j9;
            float eA = emp[1 * NL], eB = emp[2 * NL];

#define VSTEP(T_, E_) do { \
    float m0 = readlane_f(v, 0) + Tcol[0]; \
    float m1 = readlane_f(v, 1) + Tcol[1]; \
    float m2 = readlane_f(v, 2) + Tcol[2]; \
    float m3 = readlane_f(v, 3) + Tcol[3]; \
    float m4 = readlane_f(v, 4) + Tcol[4]; \
    float m5 = readlane_f(v, 5) + Tcol[5]; \
    float m6 = readlane_f(v, 6) + Tcol[6]; \
    float m7 = readlane_f(v, 7) + Tcol[7]; \
    float m8 = readlane_f(v, 8) + Tcol[8]; \
    float Ma_ = fmaxf(fmaxf(m0, m1), m2); \
    float Mb_ = fmaxf(fmaxf(m3, m4), m5); \
    float Mc_ = fmaxf(fmaxf(m6, m7), m8); \
    v = fmaxf(fmaxf(Ma_, Mb_), Mc_) + (E_); \
    if (tid < NL) s_v[(T_) * NL + tid] = v; \
} while (0)

            for (int t = 1; t < NS - 2; t += 2) {
                float eC = emp[(t + 2) * NL], eD = emp[(t + 3) * NL];
                VSTEP(t, eA);
                VSTEP(t + 1, eB);
                eA = eC; eB = eD;
            }
            VSTEP(NS - 1, eA);
#undef VSTEP
        }
        __syncthreads();
        // ---- phase 2: backpointers, parallel over t (exact ref op order + first-index ties) ----
#pragma unroll
        for (int rep = 0; rep < 2; rep++) {
            int t = 1 + tid + 256 * rep;
            if (t < NS) {
                float vp[NL], emt[NL];
#pragma unroll
                for (int i = 0; i < NL; i++) vp[i] = s_v[(t - 1) * NL + i];
#pragma unroll
                for (int j = 0; j < NL; j++) emt[j] = s_em[t * NL + j];
#pragma unroll
                for (int j = 0; j < NL; j++) {
                    float e = emt[j];
                    float val[NL];
#pragma unroll
                    for (int i = 0; i < NL; i++) val[i] = (vp[i] + s_T[i * NL + j]) + e;
                    bool c01 = val[0] >= val[1]; float m01 = c01 ? val[0] : val[1]; int i01 = c01 ? 0 : 1;
                    bool c23 = val[2] >= val[3]; float m23 = c23 ? val[2] : val[3]; int i23 = c23 ? 2 : 3;
                    bool c45 = val[4] >= val[5]; float m45 = c45 ? val[4] : val[5]; int i45 = c45 ? 4 : 5;
                    bool c67 = val[6] >= val[7]; float m67 = c67 ? val[6] : val[7]; int i67 = c67 ? 6 : 7;
                    bool ca = m01 >= m23; float ma = ca ? m01 : m23; int ia = ca ? i01 : i23;
                    bool cb = m45 >= m67; float mb = cb ? m45 : m67; int ib = cb ? i45 : i67;
                    bool cc = ma >= mb;  float mc = cc ? ma : mb;  int ic = cc ? ia : ib;
                    bool cd = mc >= val[8]; int bi = cd ? ic : 8;
                    s_bp[t * NL + j] = (unsigned char)bi;
                }
            } else if (t == NS) {
                s_bp[0 * NL + tid - 255] = 0;  // unused slot; keep writes defined
            }
        }
        __syncthreads();
        // ---- phase 3: last tag + map-composition backtrack (wave 0) ----
        if (tid < 64) {
            float bb = s_v[(NS - 1) * NL + 0] + endT[0]; int lt = 0;
#pragma unroll
            for (int jj = 1; jj < NL; jj++) {
                float fj = s_v[(NS - 1) * NL + jj] + endT[jj];
                if (fj > bb) { bb = fj; lt = jj; }
            }
            unsigned long long G[8];
#pragma unroll
            for (int r = 0; r < 8; r++) {
                int t0 = (lane * 8 + r) * NL;
                unsigned long long g = 0;
                if (lane == 0 && r == 0) {
                    g = 0x876543210ULL;   // t=0 identity (bp[0] unused)
                } else {
#pragma unroll
                    for (int x = 0; x < NL; x++) g |= (unsigned long long)s_bp[t0 + x] << (4 * x);
                }
                G[r] = g;
            }
            unsigned long long A = 0x876543210ULL;
#pragma unroll
            for (int r = 7; r >= 0; r--) {
                unsigned long long An = 0;
#pragma unroll
                for (int x = 0; x < NL; x++) {
                    int ax = (int)((A >> (4 * x)) & 15ULL);
                    int gv = (int)((G[r] >> (4 * ax)) & 15ULL);
                    An |= (unsigned long long)gv << (4 * x);
                }
                A = An;
            }
            int e = 0; int cur = lt;
            for (int ll = 63; ll >= 0; --ll) {
                if (lane == ll) e = cur;
                unsigned long long Al = readlane_u64(A, ll);
                cur = (int)((Al >> (4 * cur)) & 15ULL);
            }
            unsigned long long pw = 0; int c2 = e;
#pragma unroll
            for (int r = 7; r >= 0; r--) {
                pw |= (unsigned long long)c2 << (8 * r);
                c2 = (int)((G[r] >> (4 * c2)) & 15ULL);
            }
            *(unsigned long long*)(s_path + lane * 8) = pw;
        }
        __syncthreads();
        // ---- finalize: predict/label/correct for this batch ----
        const int* lb = label + b * NS;
        float cnt = 0.f;
#pragma unroll
        for (int q = 0; q < 2; q++) {
            int t = tid + q * 256;
            int idx = b * NS + t;
            int lab = lb[t];
            int p = (int)s_path[t];
            int pred = (lab > 0) ? p : 0;
            out[2 + idx] = (float)pred;
            out[2 + NROWS + idx] = (float)lab;
            cnt += (pred == lab) ? 1.f : 0.f;
        }
#pragma unroll
        for (int d = 1; d < 64; d <<= 1) cnt += __shfl_xor(cnt, d);
        if ((tid & 63) == 0) atomicAdd(out + 1, cnt);
    }
}

extern "C" void kernel_launch(void* const* d_in, const int* in_sizes, int n_in,
                              void* d_out, int out_size, void* d_ws, size_t ws_size,
                              hipStream_t stream) {
    const float* hidden = (const float*)d_in[0];
    const int*   label  = (const int*)d_in[1];
    const int*   mask   = (const int*)d_in[2];
    const float* W      = (const float*)d_in[3];
    const float* bias   = (const float*)d_in[4];
    const float* startT = (const float*)d_in[5];
    const float* endT   = (const float*)d_in[6];
    const float* trans  = (const float*)d_in[7];
    float* out = (float*)d_out;

    float* em = (float*)d_ws;   // EMN floats

    k_gemm<<<8192, 256, 0, stream>>>(hidden, W, bias, em, out);
    k_dp<<<128, 256, 0, stream>>>(em, label, mask, startT, endT, trans, out);
}

// Round 2
// 210.921 us; speedup vs baseline: 1.0741x; 1.0741x over previous
//
#include <hip/hip_runtime.h>
#include <hip/hip_bf16.h>

// Problem constants: B=64, S=512, H=768, L=9
#define NB 64
#define NS 512
#define NH 768
#define NL 9
#define NROWS (NB*NS)          // 32768
#define EMN (NROWS*NL)         // 294912

// per-batch LDS strides (padded off %32==0 to avoid 4-way batch bank aliasing)
#define VST  4617              // floats per batch for s_v   (>= 512*9=4608)
#define BPST 4616              // bytes  per batch for s_bp  (>= 4608)

__device__ __forceinline__ float readlane_f(float v, int l) {
    return __int_as_float(__builtin_amdgcn_readlane(__float_as_int(v), l));
}
__device__ __forceinline__ unsigned long long readlane_u64(unsigned long long v, int l) {
    unsigned int lo = (unsigned int)__builtin_amdgcn_readlane((int)(unsigned int)(v & 0xffffffffULL), l);
    unsigned int hi = (unsigned int)__builtin_amdgcn_readlane((int)(unsigned int)(v >> 32), l);
    return ((unsigned long long)hi << 32) | (unsigned long long)lo;
}
// DPP add: x += dpp_move(x, CTRL); out-of-bound source lanes contribute 0.
template <int CTRL>
__device__ __forceinline__ float dpp_add(float x) {
    int t = __builtin_amdgcn_update_dpp(0, __float_as_int(x), CTRL, 0xf, 0xf, false);
    return x + __int_as_float(t);
}
// Canonical gfx9 wave64 sum; total lands in lane 63. Pure VALU (no LDS pipe).
__device__ __forceinline__ float wave_sum_to63(float x) {
    x = dpp_add<0x111>(x);  // row_shr:1
    x = dpp_add<0x112>(x);  // row_shr:2
    x = dpp_add<0x114>(x);  // row_shr:4
    x = dpp_add<0x118>(x);  // row_shr:8  (lane15 of each row = row sum)
    x = dpp_add<0x142>(x);  // row_bcast:15
    x = dpp_add<0x143>(x);  // row_bcast:31 -> lane63 = wave sum
    return x;
}
// ds_swizzle row-broadcast: every lane receives the value held by lane
// (lane & 0x10) | I of its 32-lane group == lane I of its own 16-lane row.
// BitMode offset = (xor<<10) | (or<<5) | and  ->  (I<<5) | 0x10.
template <int I>
__device__ __forceinline__ float rowbc(float x) {
    return __int_as_float(__builtin_amdgcn_ds_swizzle(__float_as_int(x), (I << 5) | 0x10));
}

// ---------------- Kernel A: emissions GEMM (K split across waves) ----------------
// (round-0 proven version, reverted)
__global__ __launch_bounds__(256) void k_gemm(const float* __restrict__ hidden,
                                              const float* __restrict__ W,
                                              const float* __restrict__ bias,
                                              float* __restrict__ em,
                                              float* __restrict__ out) {
    __shared__ float s_part[4][4][NL];   // [wave][row][j]
    int tid = threadIdx.x;
    int lane = tid & 63;
    int w = tid >> 6;
    int bx = blockIdx.x;
    if (bx == 0 && tid == 0) { out[0] = 0.f; out[1] = 0.f; }

    int kbase = 192 * w + lane;          // + 64c, c=0..2
    float Wv[3][NL];
#pragma unroll
    for (int c = 0; c < 3; c++) {
        const float* wp = W + (size_t)(kbase + 64 * c) * NL;
#pragma unroll
        for (int j = 0; j < NL; j++) Wv[c][j] = wp[j];
    }

#pragma unroll
    for (int r = 0; r < 4; r++) {
        int row = 4 * bx + r;
        const float* hp = hidden + (size_t)row * NH + kbase;
        float h0 = hp[0], h1 = hp[64], h2 = hp[128];
        float acc[NL];
#pragma unroll
        for (int j = 0; j < NL; j++) {
            acc[j] = fmaf(h0, Wv[0][j], fmaf(h1, Wv[1][j], h2 * Wv[2][j]));
        }
#pragma unroll
        for (int j = 0; j < NL; j++) acc[j] = wave_sum_to63(acc[j]);
        if (lane == 63) {
#pragma unroll
            for (int j = 0; j < NL; j++) s_part[w][r][j] = acc[j];
        }
    }
    __syncthreads();
    if (tid < 36) {
        int r = tid / NL, j = tid % NL;
        float v = (s_part[0][r][j] + s_part[1][r][j]) +
                  (s_part[2][r][j] + s_part[3][r][j]) + bias[j];
        em[(size_t)(4 * bx + r) * NL + j] = v;
    }
}

// ---------------- Kernel B: DP + finalize (4 batches per wave via row-broadcast) ----
// blocks [0,16):  wave0 = forward chains for batches 4bx..4bx+3 (one 16-lane row each)
//                 wave1 = gold-path numerator, one 16-lane group per batch
// blocks [16,32): wave0 = 4 Viterbi value chains; then phases 2/3/finalize block-wide
__global__ __launch_bounds__(256) void k_dp(const float* __restrict__ em,
                                            const int* __restrict__ label,
                                            const int* __restrict__ mask,
                                            const float* __restrict__ startT,
                                            const float* __restrict__ endT,
                                            const float* __restrict__ trans,
                                            float* __restrict__ out) {
    __shared__ float s_T[NL * NL];
    __shared__ int s_mki[4][NS];                 // masks for the block's 4 batches
    __shared__ float s_v[4 * VST];               // viterbi value history (padded stride)
    __shared__ unsigned char s_bp[4 * BPST];     // backpointers
    __shared__ unsigned char s_path[4 * NS];     // decoded paths

    int bx = blockIdx.x;
    int tid = threadIdx.x;
    int lane = tid & 63;
    bool isfwd = bx < 16;
    int b0 = (isfwd ? bx : (bx - 16)) * 4;

    if (tid < NL * NL) s_T[tid] = trans[tid];
    if (isfwd) {
        for (int q = tid; q < 4 * NS / 4; q += 256)
            ((int4*)s_mki)[q] = ((const int4*)(mask + b0 * NS))[q];
    }
    __syncthreads();

    if (isfwd) {
        if (tid < 64) {
            // ---- forward algorithm, 4 batches (one per 16-lane row) ----
            // Bit-identical op trees vs the proven per-batch version.
            int bb = lane >> 4;
            int jcol = lane & 15;
            int jcol9 = jcol < NL ? jcol : NL - 1;
            const float* gp = em + (size_t)(b0 + bb) * (NS * NL) + jcol9;
            float Mc0 = __expf(s_T[0 * NL + jcol9]);
            float Mc1 = __expf(s_T[1 * NL + jcol9]);
            float Mc2 = __expf(s_T[2 * NL + jcol9]);
            float Mc3 = __expf(s_T[3 * NL + jcol9]);
            float Mc4 = __expf(s_T[4 * NL + jcol9]);
            float Mc5 = __expf(s_T[5 * NL + jcol9]);
            float Mc6 = __expf(s_T[6 * NL + jcol9]);
            float Mc7 = __expf(s_T[7 * NL + jcol9]);
            float Mc8 = __expf(s_T[8 * NL + jcol9]);
            float a = __expf(startT[jcol9] + gp[0]);
            int eacc = 0;

#define FBODY(EC_, KC_) do { \
    float _w0=rowbc<0>(a),_w1=rowbc<1>(a),_w2=rowbc<2>(a),_w3=rowbc<3>(a),_w4=rowbc<4>(a), \
          _w5=rowbc<5>(a),_w6=rowbc<6>(a),_w7=rowbc<7>(a),_w8=rowbc<8>(a); \
    float _p0=_w0*Mc0,_p1=_w1*Mc1,_p2=_w2*Mc2,_p3=_w3*Mc3,_p4=_w4*Mc4, \
          _p5=_w5*Mc5,_p6=_w6*Mc6,_p7=_w7*Mc7,_p8=_w8*Mc8; \
    float _s=(((_p0+_p1)+(_p2+_p3))+((_p4+_p5)+(_p6+_p7)))+_p8; \
    float _an=(EC_)*_s; \
    a = ((KC_) > 0) ? _an : a; \
} while (0)

#define FREN() do { \
    float _c0=rowbc<0>(a),_c1=rowbc<1>(a),_c2=rowbc<2>(a),_c3=rowbc<3>(a),_c4=rowbc<4>(a), \
          _c5=rowbc<5>(a),_c6=rowbc<6>(a),_c7=rowbc<7>(a),_c8=rowbc<8>(a); \
    float _cc=(((_c0+_c1)+(_c2+_c3))+((_c4+_c5)+(_c6+_c7)))+_c8; \
    int _ex=((__float_as_int(_cc)>>23)&255)-127; \
    a=ldexpf(a,-_ex); eacc+=_ex; \
} while (0)

            float e8[8]; int k8[8];
#pragma unroll
            for (int p = 0; p < 8; p++) {
                e8[p] = __expf(gp[(1 + p) * NL]);
                k8[p] = s_mki[bb][1 + p];
            }
            for (int t0 = 1; t0 <= NS - 15; t0 += 8) {   // t0 = 1,9,...,497
#pragma unroll
                for (int p = 0; p < 8; p++) {
                    int t = t0 + p;
                    float ec = e8[p]; int kc = k8[p];
                    int tn = t + 8; tn = tn > NS - 1 ? NS - 1 : tn;
                    e8[p] = __expf(gp[tn * NL]);         // prefetch 8 ahead
                    k8[p] = s_mki[bb][tn];
                    FBODY(ec, kc);
                    if (p == 7) FREN();                  // t = 8,16,...,504
                }
            }
#pragma unroll
            for (int p = 0; p < 7; p++) FBODY(e8[p], k8[p]);   // t = 505..511
#undef FBODY
#undef FREN
            float z = a * __expf(endT[jcol9]);
            float c0 = rowbc<0>(z), c1 = rowbc<1>(z), c2 = rowbc<2>(z);
            float c3 = rowbc<3>(z), c4 = rowbc<4>(z), c5 = rowbc<5>(z);
            float c6 = rowbc<6>(z), c7 = rowbc<7>(z), c8 = rowbc<8>(z);
            float c = (((c0 + c1) + (c2 + c3)) + ((c4 + c5) + (c6 + c7))) + c8;
            if (jcol == 0) {
                float lz = (float)eacc * 0.6931471805599453f + __logf(c);
                atomicAdd(out, lz * (1.0f / (float)NB));
            }
        } else if (tid < 128) {
            // ---- numerator (gold path score), one 16-lane group per batch ----
            int g = lane >> 4;
            int ll = lane & 15;
            int b = b0 + g;
            const int* lb = label + b * NS;
            const float* ge = em + (size_t)b * NS * NL;
            // pass 1: last masked label per lane (32 t's each)
            int h = 0, sl = 0;
            for (int cch = 0; cch < 4; cch++) {
                int la8[8]; int mk8[8];
#pragma unroll
                for (int r = 0; r < 8; r++) {
                    int t = ll * 32 + cch * 8 + r;
                    la8[r] = lb[t];
                    int m = s_mki[g][t];
                    if (t == 0) m = 1;
                    mk8[r] = m;
                }
#pragma unroll
                for (int r = 0; r < 8; r++) if (mk8[r] > 0) { h = 1; sl = la8[r]; }
            }
#pragma unroll
            for (int d = 1; d < 16; d <<= 1) {
                int ho = __shfl_up(h, d, 16);
                int so = __shfl_up(sl, d, 16);
                if (!h) { h = ho; sl = so; }
            }
            int lg = __shfl(sl, 15, 16);
            int incoming = __shfl_up(sl, 1, 16);
            int labz = lb[0];
            int prevr = (ll == 0) ? labz : incoming;
            float sc = 0.f;
            for (int cch = 0; cch < 4; cch++) {
                int la8[8]; int mk8[8]; float ev8[8];
#pragma unroll
                for (int r = 0; r < 8; r++) {
                    int t = ll * 32 + cch * 8 + r;
                    la8[r] = lb[t];
                    int m = s_mki[g][t];
                    if (t == 0) m = 1;
                    mk8[r] = m;
                }
#pragma unroll
                for (int r = 0; r < 8; r++) {
                    int t = ll * 32 + cch * 8 + r;
                    ev8[r] = ge[t * NL + la8[r]];
                }
#pragma unroll
                for (int r = 0; r < 8; r++) {
                    int t = ll * 32 + cch * 8 + r;
                    if (t > 0) {
                        float s = s_T[prevr * NL + la8[r]] + ev8[r];
                        sc += s * (float)mk8[r];
                    }
                    if (mk8[r] > 0) prevr = la8[r];
                }
            }
            if (ll == 0) sc += startT[labz] + ge[labz] + endT[lg];
#pragma unroll
            for (int d = 1; d < 16; d <<= 1) sc += __shfl_xor(sc, d, 16);
            if (ll == 0) atomicAdd(out, -sc * (1.0f / (float)NB));
        }
    } else {
        // ---- Viterbi phase 1: 4 value chains (one per 16-lane row), bit-exact ----
        if (tid < 64) {
            int bb = lane >> 4;
            int jcol = lane & 15;
            int jcol9 = jcol < NL ? jcol : NL - 1;
            const float* gv = em + (size_t)(b0 + bb) * (NS * NL) + jcol9;
            float Tc0 = s_T[0 * NL + jcol9];
            float Tc1 = s_T[1 * NL + jcol9];
            float Tc2 = s_T[2 * NL + jcol9];
            float Tc3 = s_T[3 * NL + jcol9];
            float Tc4 = s_T[4 * NL + jcol9];
            float Tc5 = s_T[5 * NL + jcol9];
            float Tc6 = s_T[6 * NL + jcol9];
            float Tc7 = s_T[7 * NL + jcol9];
            float Tc8 = s_T[8 * NL + jcol9];
            float v = startT[jcol9] + gv[0];
            int svbase = bb * VST + jcol;
            // lanes 9..15 write into slots later overwritten (in-order LDS) or pad
            s_v[svbase] = v;   // t = 0

#define VBODY(EC_, T_) do { \
    float _w0=rowbc<0>(v),_w1=rowbc<1>(v),_w2=rowbc<2>(v),_w3=rowbc<3>(v),_w4=rowbc<4>(v), \
          _w5=rowbc<5>(v),_w6=rowbc<6>(v),_w7=rowbc<7>(v),_w8=rowbc<8>(v); \
    float _m0=_w0+Tc0,_m1=_w1+Tc1,_m2=_w2+Tc2,_m3=_w3+Tc3,_m4=_w4+Tc4, \
          _m5=_w5+Tc5,_m6=_w6+Tc6,_m7=_w7+Tc7,_m8=_w8+Tc8; \
    float _Ma=fmaxf(fmaxf(_m0,_m1),_m2); \
    float _Mb=fmaxf(fmaxf(_m3,_m4),_m5); \
    float _Mc=fmaxf(fmaxf(_m6,_m7),_m8); \
    v = fmaxf(fmaxf(_Ma,_Mb),_Mc) + (EC_); \
    s_v[svbase + (T_) * NL] = v; \
} while (0)

            float e8[8];
#pragma unroll
            for (int p = 0; p < 8; p++) e8[p] = gv[(1 + p) * NL];
            for (int t0 = 1; t0 <= NS - 15; t0 += 8) {
#pragma unroll
                for (int p = 0; p < 8; p++) {
                    int t = t0 + p;
                    float ec = e8[p];
                    int tn = t + 8; tn = tn > NS - 1 ? NS - 1 : tn;
                    e8[p] = gv[tn * NL];
                    VBODY(ec, t);
                }
            }
#pragma unroll
            for (int p = 0; p < 7; p++) VBODY(e8[p], 505 + p);
#undef VBODY
        }
        __syncthreads();
        // ---- phase 2: backpointers, parallel over (batch, t); exact ref op order ----
        for (int it = 0; it < 8; it++) {
            int item = tid + it * 256;
            int bb = item >> 9;
            int t = item & (NS - 1);
            if (t > 0) {
                const float* vpp = s_v + bb * VST + (t - 1) * NL;
                const float* ge = em + (size_t)(b0 + bb) * (NS * NL) + t * NL;
                float vp[NL], emt[NL];
#pragma unroll
                for (int i = 0; i < NL; i++) vp[i] = vpp[i];
#pragma unroll
                for (int j = 0; j < NL; j++) emt[j] = ge[j];
#pragma unroll
                for (int j = 0; j < NL; j++) {
                    float e = emt[j];
                    float val[NL];
#pragma unroll
                    for (int i = 0; i < NL; i++) val[i] = (vp[i] + s_T[i * NL + j]) + e;
                    bool c01 = val[0] >= val[1]; float m01 = c01 ? val[0] : val[1]; int i01 = c01 ? 0 : 1;
                    bool c23 = val[2] >= val[3]; float m23 = c23 ? val[2] : val[3]; int i23 = c23 ? 2 : 3;
                    bool c45 = val[4] >= val[5]; float m45 = c45 ? val[4] : val[5]; int i45 = c45 ? 4 : 5;
                    bool c67 = val[6] >= val[7]; float m67 = c67 ? val[6] : val[7]; int i67 = c67 ? 6 : 7;
                    bool ca = m01 >= m23; float ma = ca ? m01 : m23; int ia = ca ? i01 : i23;
                    bool cb = m45 >= m67; float mb = cb ? m45 : m67; int ib = cb ? i45 : i67;
                    bool cc = ma >= mb;  float mc = cc ? ma : mb;  int ic = cc ? ia : ib;
                    bool cd = mc >= val[8]; int bi = cd ? ic : 8;
                    s_bp[bb * BPST + t * NL + j] = (unsigned char)bi;
                }
            }
        }
        __syncthreads();
        // ---- phase 3: last tag + map-composition backtrack (wave w -> batch w) ----
        {
            int w = tid >> 6;
            const float* sv = s_v + w * VST;
            const unsigned char* bpp = s_bp + w * BPST;
            unsigned char* pth = s_path + w * NS;
            float bb2 = sv[(NS - 1) * NL + 0] + endT[0]; int lt = 0;
#pragma unroll
            for (int jj = 1; jj < NL; jj++) {
                float fj = sv[(NS - 1) * NL + jj] + endT[jj];
                if (fj > bb2) { bb2 = fj; lt = jj; }
            }
            unsigned long long G[8];
#pragma unroll
            for (int r = 0; r < 8; r++) {
                int t0 = (lane * 8 + r) * NL;
                unsigned long long g = 0;
                if (lane == 0 && r == 0) {
                    g = 0x876543210ULL;   // t=0 identity (bp[0] unused)
                } else {
#pragma unroll
                    for (int x = 0; x < NL; x++) g |= (unsigned long long)bpp[t0 + x] << (4 * x);
                }
                G[r] = g;
            }
            unsigned long long A = 0x876543210ULL;
#pragma unroll
            for (int r = 7; r >= 0; r--) {
                unsigned long long An = 0;
#pragma unroll
                for (int x = 0; x < NL; x++) {
                    int ax = (int)((A >> (4 * x)) & 15ULL);
                    int gvv = (int)((G[r] >> (4 * ax)) & 15ULL);
                    An |= (unsigned long long)gvv << (4 * x);
                }
                A = An;
            }
            int e = 0; int cur = lt;
            for (int llv = 63; llv >= 0; --llv) {
                if (lane == llv) e = cur;
                unsigned long long Al = readlane_u64(A, llv);
                cur = (int)((Al >> (4 * cur)) & 15ULL);
            }
            unsigned long long pw = 0; int c2 = e;
#pragma unroll
            for (int r = 7; r >= 0; r--) {
                pw |= (unsigned long long)c2 << (8 * r);
                c2 = (int)((G[r] >> (4 * c2)) & 15ULL);
            }
            *(unsigned long long*)(pth + lane * 8) = pw;
        }
        __syncthreads();
        // ---- finalize: predict/label/correct for the block's 4 batches ----
        float cnt = 0.f;
#pragma unroll
        for (int q = 0; q < 8; q++) {
            int item = tid + q * 256;
            int bb = item >> 9;
            int t = item & (NS - 1);
            int b = b0 + bb;
            int idx = b * NS + t;
            int lab = label[idx];
            int p = (int)s_path[bb * NS + t];
            int pred = (lab > 0) ? p : 0;
            out[2 + idx] = (float)pred;
            out[2 + NROWS + idx] = (float)lab;
            cnt += (pred == lab) ? 1.f : 0.f;
        }
#pragma unroll
        for (int d = 1; d < 64; d <<= 1) cnt += __shfl_xor(cnt, d);
        if ((tid & 63) == 0) atomicAdd(out + 1, cnt);
    }
}

extern "C" void kernel_launch(void* const* d_in, const int* in_sizes, int n_in,
                              void* d_out, int out_size, void* d_ws, size_t ws_size,
                              hipStream_t stream) {
    const float* hidden = (const float*)d_in[0];
    const int*   label  = (const int*)d_in[1];
    const int*   mask   = (const int*)d_in[2];
    const float* W      = (const float*)d_in[3];
    const float* bias   = (const float*)d_in[4];
    const float* startT = (const float*)d_in[5];
    const float* endT   = (const float*)d_in[6];
    const float* trans  = (const float*)d_in[7];
    float* out = (float*)d_out;

    float* em = (float*)d_ws;   // EMN floats

    k_gemm<<<8192, 256, 0, stream>>>(hidden, W, bias, em, out);
    k_dp<<<32, 256, 0, stream>>>(em, label, mask, startT, endT, trans, out);
}